// Round 1
// baseline (815.770 us; speedup 1.0000x reference)
//
#include <hip/hip_runtime.h>

typedef _Float16 f16;
typedef _Float16 f16x8 __attribute__((ext_vector_type(8)));
typedef _Float16 f16x4 __attribute__((ext_vector_type(4)));
typedef float f32x4 __attribute__((ext_vector_type(4)));

#define NTOK 49
#define NH 16
#define HD 32
#define DIM 512
#define NWIN 64
#define NB 2048
#define MTOT (NB*NTOK)      // 100352
#define SCALE 0.17677669529663687f

// ---------------- convert fp32 -> fp16 (vectorized) ----------------
__global__ __launch_bounds__(256) void cvt_f32_f16(const float* __restrict__ s,
                                                   f16* __restrict__ d, int n4) {
    int i = blockIdx.x * 256 + threadIdx.x;
    int st = gridDim.x * 256;
    for (; i < n4; i += st) {
        float4 v = ((const float4*)s)[i];
        f16x4 o = { (f16)v.x, (f16)v.y, (f16)v.z, (f16)v.w };
        *(f16x4*)(d + (size_t)i * 4) = o;
    }
}

// ---------------- combined bias+mask table: comb[w][h][i][j] ----------------
__global__ __launch_bounds__(256) void combine_bias_mask(const float* __restrict__ rpb,
                                                         const float* __restrict__ mask,
                                                         float* __restrict__ comb) {
    int idx = blockIdx.x * 256 + threadIdx.x;
    const int total = NWIN * NH * NTOK * NTOK;
    if (idx >= total) return;
    int j = idx % NTOK;
    int rest = idx / NTOK;
    int i = rest % NTOK;
    rest /= NTOK;
    int h = rest & 15;
    int w = rest >> 4;
    int ri = i / 7, ci = i - ri * 7;
    int rj = j / 7, cj = j - rj * 7;
    int rel = (ri - rj + 6) * 13 + (ci - cj + 6);
    comb[idx] = rpb[rel * NH + h] + mask[(w * NTOK + i) * NTOK + j];
}

// ---------------- GEMM: C[m][n] = sum_k A[m][k]*B[n][k] + bias[n] ----------------
// MODE 0: N=1536, scatter-store q (*scale), k, v  as fp16 [b][h][t][d]
// MODE 1: N=512,  store fp32 to out[m*512+n]
template<int MODE>
__global__ __launch_bounds__(256) void gemm_kernel(const f16* __restrict__ A,
                                                   const f16* __restrict__ Bw,
                                                   const float* __restrict__ bias,
                                                   f16* __restrict__ qo,
                                                   f16* __restrict__ ko,
                                                   f16* __restrict__ vo,
                                                   float* __restrict__ outp) {
    __shared__ __align__(16) f16 As[128][72];
    __shared__ __align__(16) f16 Bs[128][72];

    const int tid = threadIdx.x;
    const int lane = tid & 63;
    const int wv = tid >> 6;
    const int wr = wv >> 1, wc = wv & 1;
    const int g = lane >> 4, c16 = lane & 15;
    const int m0 = blockIdx.x * 128;
    const int n0 = blockIdx.y * 128;

    f32x4 acc[4][4];
#pragma unroll
    for (int i = 0; i < 4; ++i)
#pragma unroll
        for (int j = 0; j < 4; ++j)
            acc[i][j] = (f32x4){0.f, 0.f, 0.f, 0.f};

    f16x8 stA[4], stB[4];
    // prologue: load k-step 0
#pragma unroll
    for (int it = 0; it < 4; ++it) {
        int c = it * 256 + tid;     // 0..1023 chunks of 8 f16
        int r = c >> 3, cc = c & 7;
        stA[it] = *(const f16x8*)(A + (size_t)(m0 + r) * DIM + cc * 8);
        stB[it] = *(const f16x8*)(Bw + (size_t)(n0 + r) * DIM + cc * 8);
    }

    for (int ks = 0; ks < 8; ++ks) {
        __syncthreads();   // previous compute done, LDS reusable
#pragma unroll
        for (int it = 0; it < 4; ++it) {
            int c = it * 256 + tid;
            int r = c >> 3, cc = c & 7;
            *(f16x8*)&As[r][cc * 8] = stA[it];
            *(f16x8*)&Bs[r][cc * 8] = stB[it];
        }
        __syncthreads();
        if (ks < 7) {
            int k0 = (ks + 1) * 64;
#pragma unroll
            for (int it = 0; it < 4; ++it) {
                int c = it * 256 + tid;
                int r = c >> 3, cc = c & 7;
                stA[it] = *(const f16x8*)(A + (size_t)(m0 + r) * DIM + k0 + cc * 8);
                stB[it] = *(const f16x8*)(Bw + (size_t)(n0 + r) * DIM + k0 + cc * 8);
            }
        }
#pragma unroll
        for (int kk = 0; kk < 2; ++kk) {
            f16x8 af[4], bf[4];
#pragma unroll
            for (int t = 0; t < 4; ++t)
                af[t] = *(const f16x8*)&As[wr * 64 + t * 16 + c16][kk * 32 + g * 8];
#pragma unroll
            for (int t = 0; t < 4; ++t)
                bf[t] = *(const f16x8*)&Bs[wc * 64 + t * 16 + c16][kk * 32 + g * 8];
#pragma unroll
            for (int i = 0; i < 4; ++i)
#pragma unroll
                for (int j = 0; j < 4; ++j)
                    acc[i][j] = __builtin_amdgcn_mfma_f32_16x16x32_f16(af[i], bf[j], acc[i][j], 0, 0, 0);
        }
    }

    // epilogue: C layout col = lane&15, row = (lane>>4)*4 + reg
#pragma unroll
    for (int i = 0; i < 4; ++i)
#pragma unroll
        for (int r = 0; r < 4; ++r) {
            int m = m0 + wr * 64 + i * 16 + g * 4 + r;
            int b = 0, t = 0;
            if (MODE == 0) { b = m / NTOK; t = m - b * NTOK; }
#pragma unroll
            for (int j = 0; j < 4; ++j) {
                int n = n0 + wc * 64 + j * 16 + c16;
                float v = acc[i][j][r] + bias[n];
                if (MODE == 0) {
                    int s = n >> 9;
                    int hh = (n >> 5) & 15;
                    int d = n & 31;
                    int idx = ((b * NH + hh) * NTOK + t) * HD + d;
                    if (s == 0)      qo[idx] = (f16)(v * SCALE);
                    else if (s == 1) ko[idx] = (f16)v;
                    else             vo[idx] = (f16)v;
                } else {
                    outp[(size_t)m * DIM + n] = v;
                }
            }
        }
}

// ---------------- fused window attention, 1 wave per (b,h) ----------------
__global__ __launch_bounds__(64) void attn_kernel(const f16* __restrict__ qw,
                                                  const f16* __restrict__ kw,
                                                  const f16* __restrict__ vw,
                                                  const float* __restrict__ comb,
                                                  f16* __restrict__ aout) {
    __shared__ __align__(16) f16 Qs[64][48];
    __shared__ __align__(16) f16 Ks[64][48];
    __shared__ __align__(16) f16 Vt[32][72];
    __shared__ __align__(16) f16 Ps[64][72];

    const int bid = blockIdx.x;
    const int b = bid >> 4, h = bid & 15;
    const int w = b & (NWIN - 1);
    const int l = threadIdx.x;
    const int g = l >> 4, c16 = l & 15;
    const size_t base = (size_t)(b * NH + h) * (NTOK * HD);

    // zero pads
    f16x8 z8 = {0, 0, 0, 0, 0, 0, 0, 0};
    {
        // Q/K rows 49..63, cols 0..31 (4 chunks of 8)
        for (int idx = l; idx < 15 * 4; idx += 64) {
            int rr = 49 + (idx >> 2), cc = (idx & 3) * 8;
            *(f16x8*)&Qs[rr][cc] = z8;
            *(f16x8*)&Ks[rr][cc] = z8;
        }
        f16x8* vt8 = (f16x8*)&Vt[0][0];   // 32*72/8 = 288 chunks
        for (int idx = l; idx < 288; idx += 64) vt8[idx] = z8;
    }

    // load Q, K: 49 rows x 64B = 196 16B-chunks
#pragma unroll
    for (int it = 0; it < 4; ++it) {
        int c = it * 64 + l;
        if (c < 196) {
            int row = c >> 2, cc = (c & 3) * 8;
            *(f16x8*)&Qs[row][cc] = *(const f16x8*)(qw + base + row * HD + cc);
            *(f16x8*)&Ks[row][cc] = *(const f16x8*)(kw + base + row * HD + cc);
        }
    }
    // load V row, transpose into Vt[d][t]
    if (l < NTOK) {
        f16 vr[32];
        const f16* vrow = vw + base + l * HD;
#pragma unroll
        for (int c = 0; c < 4; ++c) *(f16x8*)&vr[c * 8] = *(const f16x8*)(vrow + c * 8);
#pragma unroll
        for (int d = 0; d < 32; ++d) Vt[d][l] = vr[d];
    }
    __syncthreads();

    // S = Q K^T  (q pre-scaled): 4x4 tiles of 16x16, K=32 in one MFMA
    f16x8 qf[4], kf[4];
#pragma unroll
    for (int t = 0; t < 4; ++t) qf[t] = *(const f16x8*)&Qs[t * 16 + c16][g * 8];
#pragma unroll
    for (int t = 0; t < 4; ++t) kf[t] = *(const f16x8*)&Ks[t * 16 + c16][g * 8];

    f32x4 S[4][4];
    f32x4 zf = (f32x4){0.f, 0.f, 0.f, 0.f};
#pragma unroll
    for (int i = 0; i < 4; ++i)
#pragma unroll
        for (int j = 0; j < 4; ++j)
            S[i][j] = __builtin_amdgcn_mfma_f32_16x16x32_f16(qf[i], kf[j], zf, 0, 0, 0);

    // add bias+mask
    const float* cb = comb + (size_t)((w * NH + h) * NTOK) * NTOK;
#pragma unroll
    for (int ti = 0; ti < 4; ++ti)
#pragma unroll
        for (int r = 0; r < 4; ++r) {
            int row = ti * 16 + g * 4 + r;
            if (row < NTOK) {
#pragma unroll
                for (int tj = 0; tj < 4; ++tj) {
                    int col = tj * 16 + c16;
                    if (col < NTOK) S[ti][tj][r] += cb[row * NTOK + col];
                }
            }
        }

    // softmax rows (row i spans 16 lanes of group g, 4 tiles tj in-lane)
#pragma unroll
    for (int ti = 0; ti < 4; ++ti)
#pragma unroll
        for (int r = 0; r < 4; ++r) {
            int row = ti * 16 + g * 4 + r;
            float v0 = S[ti][0][r], v1 = S[ti][1][r], v2 = S[ti][2][r];
            float v3 = (c16 == 0) ? S[ti][3][r] : -1e30f;
            float mx = fmaxf(fmaxf(v0, v1), fmaxf(v2, v3));
#pragma unroll
            for (int mk = 1; mk < 16; mk <<= 1) mx = fmaxf(mx, __shfl_xor(mx, mk, 64));
            float p0 = __expf(v0 - mx), p1 = __expf(v1 - mx), p2 = __expf(v2 - mx);
            float p3 = (c16 == 0) ? __expf(v3 - mx) : 0.f;
            float sm = p0 + p1 + p2 + p3;
#pragma unroll
            for (int mk = 1; mk < 16; mk <<= 1) sm += __shfl_xor(sm, mk, 64);
            float inv = 1.f / sm;
            Ps[row][c16]      = (f16)(p0 * inv);
            Ps[row][16 + c16] = (f16)(p1 * inv);
            Ps[row][32 + c16] = (f16)(p2 * inv);
            Ps[row][48 + c16] = (f16)(p3 * inv);
        }
    __syncthreads();

    // O = P V : O tiles (ti in 0..3, td in 0..1), K=64 in two MFMA steps
    f32x4 O[4][2];
#pragma unroll
    for (int i = 0; i < 4; ++i) { O[i][0] = zf; O[i][1] = zf; }
#pragma unroll
    for (int c = 0; c < 2; ++c) {
        f16x8 pf[4], vf[2];
#pragma unroll
        for (int ti = 0; ti < 4; ++ti)
            pf[ti] = *(const f16x8*)&Ps[ti * 16 + c16][c * 32 + g * 8];
#pragma unroll
        for (int td = 0; td < 2; ++td)
            vf[td] = *(const f16x8*)&Vt[td * 16 + c16][c * 32 + g * 8];
#pragma unroll
        for (int ti = 0; ti < 4; ++ti)
#pragma unroll
            for (int td = 0; td < 2; ++td)
                O[ti][td] = __builtin_amdgcn_mfma_f32_16x16x32_f16(pf[ti], vf[td], O[ti][td], 0, 0, 0);
    }

    // store: aout[b*49+row][h*32 + d] fp16
#pragma unroll
    for (int ti = 0; ti < 4; ++ti)
#pragma unroll
        for (int r = 0; r < 4; ++r) {
            int row = ti * 16 + g * 4 + r;
            if (row < NTOK) {
                size_t ob = ((size_t)(b * NTOK + row)) * DIM + h * HD;
#pragma unroll
                for (int td = 0; td < 2; ++td)
                    aout[ob + td * 16 + c16] = (f16)O[ti][td][r];
            }
        }
}

// ---------------- launcher ----------------
extern "C" void kernel_launch(void* const* d_in, const int* in_sizes, int n_in,
                              void* d_out, int out_size, void* d_ws, size_t ws_size,
                              hipStream_t stream) {
    const float* x      = (const float*)d_in[0];
    const float* mask   = (const float*)d_in[1];
    const float* rpb    = (const float*)d_in[2];
    const float* qkv_w  = (const float*)d_in[3];
    const float* qkv_b  = (const float*)d_in[4];
    const float* proj_w = (const float*)d_in[5];
    const float* proj_b = (const float*)d_in[6];
    float* out = (float*)d_out;

    char* ws = (char*)d_ws;
    const size_t SZ_X16 = (size_t)MTOT * DIM * 2;           // 102,760,448
    f16* x16  = (f16*)(ws);
    f16* w16  = (f16*)(ws + SZ_X16);                        // qkv_w fp16 (1536x512)
    f16* pw16 = (f16*)(ws + SZ_X16 + 1572864);              // proj_w fp16 (512x512)
    f16* qws  = (f16*)(ws + SZ_X16 + 2097152);
    f16* kws  = (f16*)(ws + SZ_X16 + 2097152 + SZ_X16);
    f16* vws  = (f16*)(ws + SZ_X16 + 2097152 + 2 * SZ_X16);
    float* comb = (float*)(ws + SZ_X16 + 2097152 + 3 * SZ_X16);
    f16* aout = x16;    // reuse x16 buffer after QKV GEMM consumed it

    // converts
    cvt_f32_f16<<<dim3(2048), dim3(256), 0, stream>>>(x, x16, MTOT * DIM / 4);
    cvt_f32_f16<<<dim3(768), dim3(256), 0, stream>>>(qkv_w, w16, 1536 * 512 / 4);
    cvt_f32_f16<<<dim3(256), dim3(256), 0, stream>>>(proj_w, pw16, 512 * 512 / 4);

    // bias+mask table
    {
        int total = NWIN * NH * NTOK * NTOK;
        combine_bias_mask<<<dim3((total + 255) / 256), dim3(256), 0, stream>>>(rpb, mask, comb);
    }

    // QKV projection GEMM
    gemm_kernel<0><<<dim3(MTOT / 128, 1536 / 128), dim3(256), 0, stream>>>(
        x16, w16, qkv_b, qws, kws, vws, nullptr);

    // attention
    attn_kernel<<<dim3(NB * NH), dim3(64), 0, stream>>>(qws, kws, vws, comb, aout);

    // output projection GEMM
    gemm_kernel<1><<<dim3(MTOT / 128, 512 / 128), dim3(256), 0, stream>>>(
        aout, pw16, proj_b, nullptr, nullptr, nullptr, out);
}

// Round 2
// 650.896 us; speedup vs baseline: 1.2533x; 1.2533x over previous
//
#include <hip/hip_runtime.h>

typedef _Float16 f16;
typedef _Float16 f16x8 __attribute__((ext_vector_type(8)));
typedef _Float16 f16x4 __attribute__((ext_vector_type(4)));
typedef float f32x4 __attribute__((ext_vector_type(4)));

#define NTOK 49
#define NH 16
#define HD 32
#define DIM 512
#define NWIN 64
#define NB 2048
#define MTOT (NB*NTOK)      // 100352
#define SCALE 0.17677669529663687f
#define VTS 56              // vt t-stride (padded, 16B-aligned rows)

__device__ __forceinline__ void gload_lds16(const f16* g, f16* l) {
    __builtin_amdgcn_global_load_lds((const __attribute__((address_space(1))) void*)g,
                                     (__attribute__((address_space(3))) void*)l, 16, 0, 0);
}

// ---------------- convert fp32 -> fp16 (vectorized) ----------------
__global__ __launch_bounds__(256) void cvt_f32_f16(const float* __restrict__ s,
                                                   f16* __restrict__ d, int n4) {
    int i = blockIdx.x * 256 + threadIdx.x;
    int st = gridDim.x * 256;
    for (; i < n4; i += st) {
        float4 v = ((const float4*)s)[i];
        f16x4 o = { (f16)v.x, (f16)v.y, (f16)v.z, (f16)v.w };
        *(f16x4*)(d + (size_t)i * 4) = o;
    }
}

// ------- bias+mask in MFMA-fragment layout: comb2[w][h][lane][ti*4+tj][r] f32 -------
__global__ __launch_bounds__(256) void build_comb2(const float* __restrict__ rpb,
                                                   const float* __restrict__ mask,
                                                   float* __restrict__ comb2) {
    int idx = blockIdx.x * 256 + threadIdx.x;   // total = 1024 * 64 * 64
    int r4   = idx & 3;
    int tj   = (idx >> 2) & 3;
    int ti   = (idx >> 4) & 3;
    int lane = (idx >> 6) & 63;
    int wh   = idx >> 12;           // w*16 + h
    int h = wh & 15, w = wh >> 4;
    int g = lane >> 4, c16 = lane & 15;
    int row = ti * 16 + g * 4 + r4;
    int col = tj * 16 + c16;
    float v = 0.f;
    if (row < NTOK && col < NTOK) {
        int ri = row / 7, ci = row - ri * 7;
        int rj = col / 7, cj = col - rj * 7;
        int rel = (ri - rj + 6) * 13 + (ci - cj + 6);
        v = rpb[rel * NH + h] + mask[(w * NTOK + row) * NTOK + col];
    }
    comb2[idx] = v;
}

// ---------------- GEMM: C[m][n] = sum_k A[m][k]*B[n][k] + bias[n] ----------------
// global_load_lds staging (m97 pattern), linear LDS [128][64]
// MODE 0: N=1536, scatter q(*scale), k as [bid][t][d]; v TRANSPOSED as [bid][d][VTS]
// MODE 1: N=512,  fp32 out[m*512+n]
template<int MODE>
__global__ __launch_bounds__(256) void gemm_kernel(const f16* __restrict__ A,
                                                   const f16* __restrict__ Bw,
                                                   const float* __restrict__ bias,
                                                   f16* __restrict__ qo,
                                                   f16* __restrict__ ko,
                                                   f16* __restrict__ vto,
                                                   float* __restrict__ outp) {
    __shared__ __align__(16) f16 As[128][64];
    __shared__ __align__(16) f16 Bs[128][64];

    const int tid = threadIdx.x;
    const int lane = tid & 63;
    const int wv = tid >> 6;
    const int wr = wv >> 1, wc = wv & 1;
    const int g = lane >> 4, c16 = lane & 15;
    const int m0 = blockIdx.x * 128;
    const int n0 = blockIdx.y * 128;

    // staging: wave wv owns rows [wv*32, wv*32+32) = 4 chunks of 8 rows x 64 f16 (1KB each)
    const int sr = lane >> 3;
    const int sc = (lane & 7) * 8;
    const f16* gA = A + (size_t)(m0 + wv * 32 + sr) * DIM + sc;
    const f16* gB = Bw + (size_t)(n0 + wv * 32 + sr) * DIM + sc;
    f16* lA = &As[wv * 32][0];
    f16* lB = &Bs[wv * 32][0];

    f32x4 acc[4][4];
#pragma unroll
    for (int i = 0; i < 4; ++i)
#pragma unroll
        for (int j = 0; j < 4; ++j)
            acc[i][j] = (f32x4){0.f, 0.f, 0.f, 0.f};

    const int KS = DIM / 64;
    for (int ks = 0; ks < KS; ++ks) {
        const int k0 = ks * 64;
        __syncthreads();
#pragma unroll
        for (int i = 0; i < 4; ++i) {
            gload_lds16(gA + (size_t)(i * 8) * DIM + k0, lA + i * 8 * 64);
            gload_lds16(gB + (size_t)(i * 8) * DIM + k0, lB + i * 8 * 64);
        }
        __syncthreads();
#pragma unroll
        for (int kk = 0; kk < 2; ++kk) {
            f16x8 af[4], bf[4];
#pragma unroll
            for (int t = 0; t < 4; ++t)
                af[t] = *(const f16x8*)&As[wr * 64 + t * 16 + c16][kk * 32 + g * 8];
#pragma unroll
            for (int t = 0; t < 4; ++t)
                bf[t] = *(const f16x8*)&Bs[wc * 64 + t * 16 + c16][kk * 32 + g * 8];
#pragma unroll
            for (int i = 0; i < 4; ++i)
#pragma unroll
                for (int j = 0; j < 4; ++j)
                    acc[i][j] = __builtin_amdgcn_mfma_f32_16x16x32_f16(af[i], bf[j], acc[i][j], 0, 0, 0);
        }
    }

#pragma unroll
    for (int i = 0; i < 4; ++i)
#pragma unroll
        for (int r = 0; r < 4; ++r) {
            int m = m0 + wr * 64 + i * 16 + g * 4 + r;
            int b = 0, t = 0;
            if (MODE == 0) { b = m / NTOK; t = m - b * NTOK; }
#pragma unroll
            for (int j = 0; j < 4; ++j) {
                int n = n0 + wc * 64 + j * 16 + c16;
                float v = acc[i][j][r] + bias[n];
                if (MODE == 0) {
                    int s = n >> 9;
                    int hh = (n >> 5) & 15;
                    int d = n & 31;
                    int bh = b * NH + hh;
                    if (s == 0)      qo[((size_t)bh * NTOK + t) * HD + d] = (f16)(v * SCALE);
                    else if (s == 1) ko[((size_t)bh * NTOK + t) * HD + d] = (f16)v;
                    else             vto[((size_t)bh * HD + d) * VTS + t] = (f16)v;
                } else {
                    outp[(size_t)m * DIM + n] = v;
                }
            }
        }
}

// ---------------- fused window attention: 4 waves/block, 1 wave per (b,h) ----------------
__global__ __launch_bounds__(256) void attn_kernel(const f16* __restrict__ qw,
                                                   const f16* __restrict__ kw,
                                                   const f16* __restrict__ vt,
                                                   const float* __restrict__ comb2,
                                                   f16* __restrict__ aout) {
    __shared__ __align__(16) f16 Ps[4][64][72];

    const int wv = threadIdx.x >> 6;
    const int l = threadIdx.x & 63;
    const int bid = blockIdx.x * 4 + wv;
    const int b = bid >> 4, h = bid & 15;
    const int w = b & (NWIN - 1);
    const int g = l >> 4, c16 = l & 15;
    const size_t qkbase = (size_t)bid * (NTOK * HD);
    const size_t vbase = (size_t)bid * (HD * VTS);

    const f16x8 z8 = {};

    f16x8 qf[4], kf[4];
#pragma unroll
    for (int t = 0; t < 4; ++t) {
        int row = t * 16 + c16;
        f16x8 q = z8, k = z8;
        if (row < NTOK) {
            q = *(const f16x8*)(qw + qkbase + row * HD + g * 8);
            k = *(const f16x8*)(kw + qkbase + row * HD + g * 8);
        }
        qf[t] = q; kf[t] = k;
    }

    const float* cb = comb2 + (((size_t)(w * NH + h) * 64 + l) << 6);
    f32x4 S[4][4];
#pragma unroll
    for (int i = 0; i < 4; ++i)
#pragma unroll
        for (int j = 0; j < 4; ++j)
            S[i][j] = *(const f32x4*)(cb + (i * 4 + j) * 4);
#pragma unroll
    for (int i = 0; i < 4; ++i)
#pragma unroll
        for (int j = 0; j < 4; ++j)
            S[i][j] = __builtin_amdgcn_mfma_f32_16x16x32_f16(qf[i], kf[j], S[i][j], 0, 0, 0);

#pragma unroll
    for (int ti = 0; ti < 4; ++ti)
#pragma unroll
        for (int r = 0; r < 4; ++r) {
            int row = ti * 16 + g * 4 + r;
            float v0 = S[ti][0][r], v1 = S[ti][1][r], v2 = S[ti][2][r];
            float v3 = (c16 == 0) ? S[ti][3][r] : -1e30f;
            float mx = fmaxf(fmaxf(v0, v1), fmaxf(v2, v3));
#pragma unroll
            for (int mk = 1; mk < 16; mk <<= 1) mx = fmaxf(mx, __shfl_xor(mx, mk, 64));
            float p0 = __expf(v0 - mx), p1 = __expf(v1 - mx), p2 = __expf(v2 - mx);
            float p3 = (c16 == 0) ? __expf(v3 - mx) : 0.f;
            float sm = p0 + p1 + p2 + p3;
#pragma unroll
            for (int mk = 1; mk < 16; mk <<= 1) sm += __shfl_xor(sm, mk, 64);
            float inv = 1.f / sm;
            Ps[wv][row][c16]      = (f16)(p0 * inv);
            Ps[wv][row][16 + c16] = (f16)(p1 * inv);
            Ps[wv][row][32 + c16] = (f16)(p2 * inv);
            Ps[wv][row][48 + c16] = (f16)(p3 * inv);
        }
    __syncthreads();

    f32x4 O[4][2];
    const f32x4 zf = (f32x4){0.f, 0.f, 0.f, 0.f};
#pragma unroll
    for (int i = 0; i < 4; ++i) { O[i][0] = zf; O[i][1] = zf; }
#pragma unroll
    for (int c = 0; c < 2; ++c) {
        f16x8 pf[4], vf[2];
#pragma unroll
        for (int ti = 0; ti < 4; ++ti)
            pf[ti] = *(const f16x8*)&Ps[wv][ti * 16 + c16][c * 32 + g * 8];
        int tcol = c * 32 + g * 8;
#pragma unroll
        for (int td = 0; td < 2; ++td) {
            f16x8 vv = z8;
            if (tcol < VTS)
                vv = *(const f16x8*)(vt + vbase + (size_t)(td * 16 + c16) * VTS + tcol);
            vf[td] = vv;
        }
#pragma unroll
        for (int ti = 0; ti < 4; ++ti)
#pragma unroll
            for (int td = 0; td < 2; ++td)
                O[ti][td] = __builtin_amdgcn_mfma_f32_16x16x32_f16(pf[ti], vf[td], O[ti][td], 0, 0, 0);
    }

#pragma unroll
    for (int ti = 0; ti < 4; ++ti)
#pragma unroll
        for (int r = 0; r < 4; ++r) {
            int row = ti * 16 + g * 4 + r;
            if (row < NTOK) {
                size_t ob = ((size_t)(b * NTOK + row)) * DIM + h * HD;
                aout[ob + c16]      = (f16)O[ti][0][r];
                aout[ob + 16 + c16] = (f16)O[ti][1][r];
            }
        }
}

// ---------------- launcher ----------------
extern "C" void kernel_launch(void* const* d_in, const int* in_sizes, int n_in,
                              void* d_out, int out_size, void* d_ws, size_t ws_size,
                              hipStream_t stream) {
    const float* x      = (const float*)d_in[0];
    const float* mask   = (const float*)d_in[1];
    const float* rpb    = (const float*)d_in[2];
    const float* qkv_w  = (const float*)d_in[3];
    const float* qkv_b  = (const float*)d_in[4];
    const float* proj_w = (const float*)d_in[5];
    const float* proj_b = (const float*)d_in[6];
    float* out = (float*)d_out;

    char* ws = (char*)d_ws;
    size_t o = 0;
    f16* x16   = (f16*)(ws + o); o += (size_t)MTOT * DIM * 2;
    f16* w16   = (f16*)(ws + o); o += (size_t)1536 * 512 * 2;
    f16* pw16  = (f16*)(ws + o); o += (size_t)512 * 512 * 2;
    f16* qws   = (f16*)(ws + o); o += (size_t)NB * NH * NTOK * HD * 2;
    f16* kws   = (f16*)(ws + o); o += (size_t)NB * NH * NTOK * HD * 2;
    f16* vtws  = (f16*)(ws + o); o += (size_t)NB * NH * HD * VTS * 2;
    float* cb2 = (float*)(ws + o);
    f16* aout = x16;   // x16 dead after QKV GEMM

    cvt_f32_f16<<<dim3(2048), dim3(256), 0, stream>>>(x, x16, MTOT * DIM / 4);
    cvt_f32_f16<<<dim3(768), dim3(256), 0, stream>>>(qkv_w, w16, 1536 * 512 / 4);
    cvt_f32_f16<<<dim3(256), dim3(256), 0, stream>>>(proj_w, pw16, 512 * 512 / 4);

    build_comb2<<<dim3(16384), dim3(256), 0, stream>>>(rpb, mask, cb2);

    gemm_kernel<0><<<dim3(MTOT / 128, 1536 / 128), dim3(256), 0, stream>>>(
        x16, w16, qkv_b, qws, kws, vtws, nullptr);

    attn_kernel<<<dim3(NB * NH / 4), dim3(256), 0, stream>>>(qws, kws, vtws, cb2, aout);

    gemm_kernel<1><<<dim3(MTOT / 128, 512 / 128), dim3(256), 0, stream>>>(
        aout, pw16, proj_b, nullptr, nullptr, nullptr, out);
}